// Round 4
// baseline (183.142 us; speedup 1.0000x reference)
//
#include <hip/hip_runtime.h>
#include <hip/hip_bf16.h>

constexpr int kB    = 8;
constexpr int kN    = 512;
constexpr int kFIN  = 256;
constexpr int kFOUT = 128;
constexpr int kNE   = 10;
constexpr float kALPHA = 0.2f;
constexpr float kNEG   = -9e15f;

// ---------------------------------------------------------------------------
// Kernel 1: typed projection, W-slice resident in LDS.
// Block = 32 rows x 32-out slice. Grid = 128 row-stripes x 4 slices = 512.
// Thread = (f4 = (tid&7)*4 outs, rg = tid>>3 row). Inner loop: LDS only.
// ---------------------------------------------------------------------------
__global__ __launch_bounds__(256) void proj_kernel(
    const float* __restrict__ node_rep,  // (B*N, FIN)
    const float* __restrict__ mask,      // (T, B*N)
    const float* __restrict__ W,         // (T, FIN, FOUT)
    const float* __restrict__ bias,      // (T, FOUT)
    float* __restrict__ h)               // (B*N, FOUT)
{
    __shared__ float ws3[3 * kFIN * 32]; // 96 KB  [t][k][o-slice]
    __shared__ float xs[32][kFIN + 4];   // 33 KB  pad -> bank spread

    const int tid   = threadIdx.x;
    const int slice = blockIdx.x & 3;
    const int o0    = slice * 32;
    const int row0  = (blockIdx.x >> 2) * 32;

    // stage W slice: 3*256*32 floats = 6144 float4
    #pragma unroll
    for (int it = 0; it < 24; ++it) {
        int idx = tid + it * 256;            // < 6144
        int oq  = idx & 7;
        int k   = (idx >> 3) & 255;
        int t   = idx >> 11;
        float4 v = *(const float4*)&W[((size_t)(t * kFIN + k)) * kFOUT + o0 + oq * 4];
        *(float4*)&ws3[(t * kFIN + k) * 32 + oq * 4] = v;
    }
    // stage x tile: 32*256 floats = 2048 float4
    #pragma unroll
    for (int it = 0; it < 8; ++it) {
        int idx = tid + it * 256;            // < 2048
        int r   = idx >> 6;
        int kq  = idx & 63;
        float4 v = *(const float4*)&node_rep[((size_t)(row0 + r)) * kFIN + kq * 4];
        *(float4*)&xs[r][kq * 4] = v;
    }
    __syncthreads();

    const int f4 = (tid & 7) * 4;
    const int rg = tid >> 3;

    float4 a0 = {0,0,0,0}, a1v = {0,0,0,0}, a2v = {0,0,0,0};
    #pragma unroll 4
    for (int k = 0; k < kFIN; ++k) {
        float  x  = xs[rg][k];
        float4 w0 = *(const float4*)&ws3[(0 * kFIN + k) * 32 + f4];
        float4 w1 = *(const float4*)&ws3[(1 * kFIN + k) * 32 + f4];
        float4 w2 = *(const float4*)&ws3[(2 * kFIN + k) * 32 + f4];
        a0.x  = fmaf(w0.x, x, a0.x);  a0.y  = fmaf(w0.y, x, a0.y);
        a0.z  = fmaf(w0.z, x, a0.z);  a0.w  = fmaf(w0.w, x, a0.w);
        a1v.x = fmaf(w1.x, x, a1v.x); a1v.y = fmaf(w1.y, x, a1v.y);
        a1v.z = fmaf(w1.z, x, a1v.z); a1v.w = fmaf(w1.w, x, a1v.w);
        a2v.x = fmaf(w2.x, x, a2v.x); a2v.y = fmaf(w2.y, x, a2v.y);
        a2v.z = fmaf(w2.z, x, a2v.z); a2v.w = fmaf(w2.w, x, a2v.w);
    }

    const int row = row0 + rg;
    const float m0 = mask[row];
    const float m1 = mask[kB * kN + row];
    const float m2 = mask[2 * kB * kN + row];
    const float4 b0 = *(const float4*)&bias[o0 + f4];
    const float4 b1 = *(const float4*)&bias[kFOUT + o0 + f4];
    const float4 b2 = *(const float4*)&bias[2 * kFOUT + o0 + f4];

    float4 hv;
    hv.x = m0 * (a0.x + b0.x) + m1 * (a1v.x + b1.x) + m2 * (a2v.x + b2.x);
    hv.y = m0 * (a0.y + b0.y) + m1 * (a1v.y + b1.y) + m2 * (a2v.y + b2.y);
    hv.z = m0 * (a0.z + b0.z) + m1 * (a1v.z + b1.z) + m2 * (a2v.z + b2.z);
    hv.w = m0 * (a0.w + b0.w) + m1 * (a1v.w + b1.w) + m2 * (a2v.w + b2.w);
    *(float4*)&h[(size_t)row * kFOUT + o0 + f4] = hv;
}

// ---------------------------------------------------------------------------
// Kernel 2: s1[row]=h.a1+a_b, s2[row]=h.a2 (wave per row) + emb.a2 table
// ---------------------------------------------------------------------------
__global__ __launch_bounds__(256) void sk_kernel(
    const float* __restrict__ h,
    const float* __restrict__ a1,
    const float* __restrict__ a2,
    const float* __restrict__ a_b,
    const float* __restrict__ emb,
    float* __restrict__ s1,
    float* __restrict__ s2,
    float* __restrict__ emb_a2)
{
    const int tid = threadIdx.x;

    if (blockIdx.x == (kB * kN) / 4) {
        const int e = tid >> 4, l = tid & 15;
        if (e <= kNE) {
            float p = 0.f;
            #pragma unroll
            for (int k = 0; k < 8; ++k)
                p += emb[e * kFOUT + l + k * 16] * a2[l + k * 16];
            #pragma unroll
            for (int off = 8; off; off >>= 1) p += __shfl_xor(p, off);
            if (l == 0) emb_a2[e] = p;
        }
        return;
    }

    const int row  = blockIdx.x * 4 + (tid >> 6);
    const int lane = tid & 63;
    const float v0 = h[(size_t)row * kFOUT + lane];
    const float v1 = h[(size_t)row * kFOUT + 64 + lane];
    float p1 = v0 * a1[lane] + v1 * a1[64 + lane];
    float p2 = v0 * a2[lane] + v1 * a2[64 + lane];
    #pragma unroll
    for (int off = 32; off; off >>= 1) {
        p1 += __shfl_down(p1, off);
        p2 += __shfl_down(p2, off);
    }
    if (lane == 0) {
        s1[row] = p1 + a_b[0];
        s2[row] = p2;
    }
}

// ---------------------------------------------------------------------------
// Kernel 3: 32 i-rows per block, j-half per block (grid 8*16*2 = 256).
// Full-row scores+softmax+histogram (both halves), dense attn@h over own
// j-half with h staged in LDS chunks (register prefetch). jh=0 adds the
// emb-type correction and writes to out; jh=1 writes to p1.
// ---------------------------------------------------------------------------
__global__ __launch_bounds__(256) void attn_kernel(
    const int*   __restrict__ adj,     // (B, N, N)
    const float* __restrict__ emb,     // (NE+1, FOUT)
    const float* __restrict__ h,       // (B*N, FOUT)
    const float* __restrict__ s1,      // (B*N) a_b folded
    const float* __restrict__ s2,      // (B*N)
    const float* __restrict__ emb_a2g, // (16)
    float* __restrict__ outp,          // (B*N, FOUT) partial jh=0
    float* __restrict__ p1)            // (B*N, FOUT) partial jh=1
{
    __shared__ float         sc[32][kN + 4];      // 66 KB scores -> attn
    __shared__ unsigned char adj8[32][kN];        // 16 KB
    __shared__ float         hs[64][kFOUT];       // 32 KB h chunk
    __shared__ float         s2s[kN];
    __shared__ float         s1s[32];
    __shared__ float         wsum[32][16];
    __shared__ float         ea2[16];

    const int tid = threadIdx.x;
    const int jh  = blockIdx.x & 1;
    const int is  = (blockIdx.x >> 1) & 15;
    const int b   = blockIdx.x >> 5;
    const int i0  = is * 32;

    if (tid < 16) ea2[tid] = emb_a2g[tid];
    if (tid < 32) s1s[tid] = s1[b * kN + i0 + tid];
    s2s[tid]       = s2[b * kN + tid];
    s2s[tid + 256] = s2[b * kN + tid + 256];
    __syncthreads();

    // Phase A: full-row scores
    const int* adjb = adj + ((size_t)(b * kN + i0)) * kN;
    #pragma unroll 4
    for (int it = 0; it < 64; ++it) {
        int idx = tid + it * 256;
        int r = idx >> 9, j = idx & (kN - 1);
        int a = adjb[(size_t)r * kN + j];
        float s = s1s[r] + s2s[j] + ea2[a];
        s = (s > 0.f) ? s : kALPHA * s;
        sc[r][j]   = (a > 0) ? s : kNEG;
        adj8[r][j] = (unsigned char)a;
    }
    __syncthreads();

    // Phase B: softmax + 10-bin histogram, wave per 8 rows
    const int wave = tid >> 6, lane = tid & 63;
    for (int rr = 0; rr < 8; ++rr) {
        const int r = wave * 8 + rr;
        float v[8];
        #pragma unroll
        for (int k = 0; k < 8; ++k) v[k] = sc[r][lane + k * 64];
        float m = v[0];
        #pragma unroll
        for (int k = 1; k < 8; ++k) m = fmaxf(m, v[k]);
        #pragma unroll
        for (int off = 32; off; off >>= 1) m = fmaxf(m, __shfl_xor(m, off));
        float sum = 0.f;
        #pragma unroll
        for (int k = 0; k < 8; ++k) { v[k] = __expf(v[k] - m); sum += v[k]; }
        #pragma unroll
        for (int off = 32; off; off >>= 1) sum += __shfl_xor(sum, off);
        const float inv = 1.0f / sum;
        unsigned char a8[8];
        #pragma unroll
        for (int k = 0; k < 8; ++k) {
            v[k] *= inv;
            sc[r][lane + k * 64] = v[k];
            a8[k] = adj8[r][lane + k * 64];
        }
        for (int e = 1; e <= kNE; ++e) {
            float p = 0.f;
            #pragma unroll
            for (int k = 0; k < 8; ++k) p += (a8[k] == (unsigned char)e) ? v[k] : 0.f;
            #pragma unroll
            for (int off = 32; off; off >>= 1) p += __shfl_xor(p, off);
            if (lane == 0) wsum[r][e] = p;
        }
    }
    __syncthreads();

    // Phase C: dense attn @ h over own j-half, 4 chunks of 64 j.
    const int f4 = (tid & 31) * 4;
    const int rg = tid >> 5;            // 8 groups, 4 rows each
    const int r0 = rg * 4;
    const int jbase = jh * 256;
    const float* hb = h + ((size_t)(b * kN + jbase)) * kFOUT;

    // stage chunk 0
    #pragma unroll
    for (int t2 = 0; t2 < 8; ++t2) {
        int sidx = tid + t2 * 256;       // < 2048
        int jj = sidx >> 5, fq = sidx & 31;
        *(float4*)&hs[jj][fq * 4] = *(const float4*)&hb[(size_t)jj * kFOUT + fq * 4];
    }
    __syncthreads();

    float4 acc0 = {0,0,0,0}, acc1 = {0,0,0,0}, acc2 = {0,0,0,0}, acc3 = {0,0,0,0};

    for (int c = 0; c < 4; ++c) {
        // issue next-chunk loads early (latency hides under compute)
        float4 pre[8];
        if (c < 3) {
            #pragma unroll
            for (int t2 = 0; t2 < 8; ++t2) {
                int sidx = tid + t2 * 256;
                int jj = sidx >> 5, fq = sidx & 31;
                pre[t2] = *(const float4*)&hb[((size_t)(c + 1) * 64 + jj) * kFOUT + fq * 4];
            }
        }
        const int jc = jbase + c * 64;
        #pragma unroll 2
        for (int jj = 0; jj < 64; ++jj) {
            float4 hv = *(const float4*)&hs[jj][f4];
            float w0 = sc[r0 + 0][jc + jj];
            float w1 = sc[r0 + 1][jc + jj];
            float w2 = sc[r0 + 2][jc + jj];
            float w3 = sc[r0 + 3][jc + jj];
            acc0.x = fmaf(w0, hv.x, acc0.x); acc0.y = fmaf(w0, hv.y, acc0.y);
            acc0.z = fmaf(w0, hv.z, acc0.z); acc0.w = fmaf(w0, hv.w, acc0.w);
            acc1.x = fmaf(w1, hv.x, acc1.x); acc1.y = fmaf(w1, hv.y, acc1.y);
            acc1.z = fmaf(w1, hv.z, acc1.z); acc1.w = fmaf(w1, hv.w, acc1.w);
            acc2.x = fmaf(w2, hv.x, acc2.x); acc2.y = fmaf(w2, hv.y, acc2.y);
            acc2.z = fmaf(w2, hv.z, acc2.z); acc2.w = fmaf(w2, hv.w, acc2.w);
            acc3.x = fmaf(w3, hv.x, acc3.x); acc3.y = fmaf(w3, hv.y, acc3.y);
            acc3.z = fmaf(w3, hv.z, acc3.z); acc3.w = fmaf(w3, hv.w, acc3.w);
        }
        __syncthreads();
        if (c < 3) {
            #pragma unroll
            for (int t2 = 0; t2 < 8; ++t2) {
                int sidx = tid + t2 * 256;
                int jj = sidx >> 5, fq = sidx & 31;
                *(float4*)&hs[jj][fq * 4] = pre[t2];
            }
            __syncthreads();
        }
    }

    // Phase D: partial write (+ correction on jh==0)
    float4 accs[4] = {acc0, acc1, acc2, acc3};
    #pragma unroll
    for (int rr = 0; rr < 4; ++rr) {
        float4 a = accs[rr];
        const size_t oidx = ((size_t)(b * kN + i0 + r0 + rr)) * kFOUT + f4;
        if (jh == 0) {
            for (int e = 1; e <= kNE; ++e) {
                float  wv = wsum[r0 + rr][e];
                float4 ev = *(const float4*)&emb[e * kFOUT + f4];
                a.x = fmaf(wv, ev.x, a.x); a.y = fmaf(wv, ev.y, a.y);
                a.z = fmaf(wv, ev.z, a.z); a.w = fmaf(wv, ev.w, a.w);
            }
            *(float4*)&outp[oidx] = a;
        } else {
            *(float4*)&p1[oidx] = a;
        }
    }
}

// ---------------------------------------------------------------------------
// Kernel 4: out = elu(out_partial + p1)
// ---------------------------------------------------------------------------
__global__ __launch_bounds__(256) void epi_kernel(
    const float* __restrict__ p1,
    float* __restrict__ out)
{
    const int gi = blockIdx.x * 256 + threadIdx.x;   // float4 index
    float4 a = *(const float4*)&out[(size_t)gi * 4];
    float4 c = *(const float4*)&p1[(size_t)gi * 4];
    a.x += c.x; a.y += c.y; a.z += c.z; a.w += c.w;
    a.x = (a.x > 0.f) ? a.x : expm1f(a.x);
    a.y = (a.y > 0.f) ? a.y : expm1f(a.y);
    a.z = (a.z > 0.f) ? a.z : expm1f(a.z);
    a.w = (a.w > 0.f) ? a.w : expm1f(a.w);
    *(float4*)&out[(size_t)gi * 4] = a;
}

// ---------------------------------------------------------------------------
extern "C" void kernel_launch(void* const* d_in, const int* in_sizes, int n_in,
                              void* d_out, int out_size, void* d_ws, size_t ws_size,
                              hipStream_t stream) {
    const float* node_rep = (const float*)d_in[0];
    const float* mask     = (const float*)d_in[1];
    const int*   adj      = (const int*)  d_in[2];
    const float* W        = (const float*)d_in[3];
    const float* bias     = (const float*)d_in[4];
    const float* a1       = (const float*)d_in[5];
    const float* a2       = (const float*)d_in[6];
    const float* a_b      = (const float*)d_in[7];
    const float* emb      = (const float*)d_in[8];
    float* out = (float*)d_out;

    float* ws     = (float*)d_ws;
    float* h      = ws;                            // B*N*FOUT   (2 MB)
    float* s1     = h + (size_t)kB * kN * kFOUT;   // B*N
    float* s2     = s1 + kB * kN;                  // B*N
    float* emb_a2 = s2 + kB * kN;                  // 16
    float* p1     = emb_a2 + 16;                   // B*N*FOUT   (2 MB)

    proj_kernel<<<512, 256, 0, stream>>>(node_rep, mask, W, bias, h);
    sk_kernel<<<(kB * kN) / 4 + 1, 256, 0, stream>>>(h, a1, a2, a_b, emb, s1, s2, emb_a2);
    attn_kernel<<<kB * 16 * 2, 256, 0, stream>>>(adj, emb, h, s1, s2, emb_a2, out, p1);
    epi_kernel<<<(kB * kN * kFOUT) / (256 * 4), 256, 0, stream>>>(p1, out);
}

// Round 5
// 128.472 us; speedup vs baseline: 1.4255x; 1.4255x over previous
//
#include <hip/hip_runtime.h>

constexpr int kB    = 8;
constexpr int kN    = 512;
constexpr int kFIN  = 256;
constexpr int kFOUT = 128;
constexpr int kNE   = 10;
constexpr int kBN   = kB * kN;
constexpr float kALPHA = 0.2f;
constexpr float kNEG   = -9e15f;

// ---------------------------------------------------------------------------
// Kernel 1: typed projection + s1/s2 + emb.a2 table.
// Grid 512 x 512 threads. 8 rows/block; thread = (o = tid&127, kq = tid>>7).
// Each thread: 8 rows x 1 out x 3 types over a 64-wide k-quarter = 24 acc.
// W streamed from L2 coalesced (each element once per block); x broadcast
// from 8 KB LDS. Partials combined via LDS, then mask/bias, h store, and
// wave-per-row s1/s2 reductions. Low LDS (44 KB) -> 2 blocks/CU, 16 waves.
// ---------------------------------------------------------------------------
__global__ __launch_bounds__(512) void proj_kernel(
    const float* __restrict__ node_rep,  // (B*N, FIN)
    const float* __restrict__ mask,      // (T, B*N)
    const float* __restrict__ W,         // (T, FIN, FOUT)
    const float* __restrict__ bias,      // (T, FOUT)
    const float* __restrict__ a1,
    const float* __restrict__ a2,
    const float* __restrict__ a_b,
    const float* __restrict__ emb,       // (NE+1, FOUT)
    float* __restrict__ h,               // (B*N, FOUT)
    float* __restrict__ s1,              // (B*N) a_b folded
    float* __restrict__ s2,              // (B*N)
    float* __restrict__ emb_a2)          // (16)
{
    __shared__ float xs[8][kFIN];          //  8 KB
    __shared__ float parts[9][8][kFOUT];   // 36 KB: [(kq-1)*3 + t][r][o]

    const int tid  = threadIdx.x;
    const int row0 = blockIdx.x * 8;
    const int o    = tid & 127;
    const int kq   = tid >> 7;             // 0..3 -> k in [kq*64, kq*64+64)

    {   // stage x tile (coalesced float4)
        const int r = tid >> 6, q = tid & 63;
        *(float4*)&xs[r][q * 4] =
            *(const float4*)&node_rep[(size_t)(row0 + r) * kFIN + q * 4];
    }
    __syncthreads();

    float acc[3][8];
    #pragma unroll
    for (int t = 0; t < 3; ++t)
        #pragma unroll
        for (int r = 0; r < 8; ++r) acc[t][r] = 0.f;

    const float* Wo = W + o;
    #pragma unroll 2
    for (int i4 = 0; i4 < 16; ++i4) {
        const int kb = kq * 64 + i4 * 4;
        float4 xv[8];
        #pragma unroll
        for (int r = 0; r < 8; ++r)        // broadcast b128 reads (conflict-free)
            xv[r] = *(const float4*)&xs[r][kb];
        #pragma unroll
        for (int c = 0; c < 4; ++c) {
            const int k = kb + c;
            const float w0 = Wo[(0 * kFIN + k) * kFOUT];   // coalesced over o
            const float w1 = Wo[(1 * kFIN + k) * kFOUT];
            const float w2 = Wo[(2 * kFIN + k) * kFOUT];
            #pragma unroll
            for (int r = 0; r < 8; ++r) {
                const float x = ((const float*)&xv[r])[c];
                acc[0][r] = fmaf(w0, x, acc[0][r]);
                acc[1][r] = fmaf(w1, x, acc[1][r]);
                acc[2][r] = fmaf(w2, x, acc[2][r]);
            }
        }
    }

    if (kq > 0) {
        #pragma unroll
        for (int t = 0; t < 3; ++t)
            #pragma unroll
            for (int r = 0; r < 8; ++r)
                parts[(kq - 1) * 3 + t][r][o] = acc[t][r];   // lanes o: stride-1
    }
    __syncthreads();

    if (kq == 0) {
        #pragma unroll
        for (int r = 0; r < 8; ++r) {
            const int row = row0 + r;
            float hv = 0.f;
            #pragma unroll
            for (int t = 0; t < 3; ++t) {
                const float s = acc[t][r] + parts[t][r][o] + parts[3 + t][r][o]
                              + parts[6 + t][r][o] + bias[t * kFOUT + o];
                hv = fmaf(mask[t * kBN + row], s, hv);
            }
            h[(size_t)row * kFOUT + o] = hv;
            parts[0][r][o] = hv;           // hsred: slot already consumed above
        }
    }
    __syncthreads();

    // s1/s2: wave per row (8 waves = 8 rows)
    {
        const int r = tid >> 6, lane = tid & 63;
        const float v0 = parts[0][r][lane];
        const float v1 = parts[0][r][64 + lane];
        float p1 = v0 * a1[lane] + v1 * a1[64 + lane];
        float p2 = v0 * a2[lane] + v1 * a2[64 + lane];
        #pragma unroll
        for (int off = 32; off; off >>= 1) {
            p1 += __shfl_down(p1, off);
            p2 += __shfl_down(p2, off);
        }
        if (lane == 0) {
            s1[row0 + r] = p1 + a_b[0];
            s2[row0 + r] = p2;
        }
    }

    // emb.a2 table once (block 0): 11 rows x 16 lanes
    if (blockIdx.x == 0 && tid < 176) {
        const int e = tid >> 4, l = tid & 15;
        float p = 0.f;
        #pragma unroll
        for (int k8 = 0; k8 < 8; ++k8)
            p += emb[e * kFOUT + l + k8 * 16] * a2[l + k8 * 16];
        #pragma unroll
        for (int off = 8; off; off >>= 1) p += __shfl_xor(p, off);
        if (l == 0) emb_a2[e] = p;
    }
}

// ---------------------------------------------------------------------------
// Kernel 2: scores + softmax + edge-type histogram + dense attn@h + ELU.
// Grid 512 x 512 threads. 8 i-rows/block, full j-range (no epilogue kernel).
//   out[i,f] = elu( sum_j attn[i,j]*h[j,f] + sum_e wsum[i,e]*emb[e,f] )
// h streamed from L2 (read once per block); adj kept as int4 in LDS (no
// byte-wide LDS traffic). LDS 35 KB -> 2 blocks/CU, 16 waves.
// ---------------------------------------------------------------------------
__global__ __launch_bounds__(512) void attn_kernel(
    const int*   __restrict__ adj,     // (B, N, N)
    const float* __restrict__ emb,     // (NE+1, FOUT)
    const float* __restrict__ h,       // (B*N, FOUT)
    const float* __restrict__ s1,      // (B*N) a_b folded
    const float* __restrict__ s2,      // (B*N)
    const float* __restrict__ emb_a2g, // (16)
    float* __restrict__ out)           // (B*N, FOUT)
{
    __shared__ float sc[8][kN + 4];    // 16.5 KB scores -> attn (stride 516)
    __shared__ int   adjs[8][kN];      // 16 KB (reused as combine scratch)
    __shared__ float s2s[kN];
    __shared__ float s1s[8];
    __shared__ float wsum[8][16];
    __shared__ float ea2[16];

    const int tid = threadIdx.x;
    const int b   = blockIdx.x >> 6;          // / (kN/8)
    const int i0  = (blockIdx.x & 63) * 8;

    if (tid < 16) ea2[tid] = emb_a2g[tid];
    if (tid < 8)  s1s[tid] = s1[b * kN + i0 + tid];
    s2s[tid] = s2[b * kN + tid];
    __syncthreads();

    // Phase A: scores, 4 j per thread (int4/float4 LDS traffic only)
    const int* adjb = adj + ((size_t)(b * kN + i0)) * kN;
    #pragma unroll
    for (int it = 0; it < 2; ++it) {
        const int idx = tid + it * 512;       // quad index 0..1023
        const int r = idx >> 7, jq = idx & 127;
        const int4   av  = *(const int4*)&adjb[(size_t)r * kN + jq * 4];
        const float4 s2v = *(const float4*)&s2s[jq * 4];
        const float  sr  = s1s[r];
        float4 sv;
        float s;
        s = sr + s2v.x + ea2[av.x]; s = s > 0.f ? s : kALPHA * s; sv.x = av.x > 0 ? s : kNEG;
        s = sr + s2v.y + ea2[av.y]; s = s > 0.f ? s : kALPHA * s; sv.y = av.y > 0 ? s : kNEG;
        s = sr + s2v.z + ea2[av.z]; s = s > 0.f ? s : kALPHA * s; sv.z = av.z > 0 ? s : kNEG;
        s = sr + s2v.w + ea2[av.w]; s = s > 0.f ? s : kALPHA * s; sv.w = av.w > 0 ? s : kNEG;
        *(float4*)&sc[r][jq * 4]  = sv;
        *(int4*)&adjs[r][jq * 4]  = av;
    }
    __syncthreads();

    // Phase B: softmax + 10-bin histogram, wave per row (8 waves = 8 rows)
    {
        const int r = tid >> 6, lane = tid & 63;
        float v[8]; int av[8];
        #pragma unroll
        for (int k = 0; k < 8; ++k) {
            v[k]  = sc[r][lane + k * 64];
            av[k] = adjs[r][lane + k * 64];
        }
        float m = v[0];
        #pragma unroll
        for (int k = 1; k < 8; ++k) m = fmaxf(m, v[k]);
        #pragma unroll
        for (int off = 32; off; off >>= 1) m = fmaxf(m, __shfl_xor(m, off));
        float sum = 0.f;
        #pragma unroll
        for (int k = 0; k < 8; ++k) { v[k] = __expf(v[k] - m); sum += v[k]; }
        #pragma unroll
        for (int off = 32; off; off >>= 1) sum += __shfl_xor(sum, off);
        const float inv = 1.0f / sum;
        #pragma unroll
        for (int k = 0; k < 8; ++k) {
            v[k] *= inv;
            sc[r][lane + k * 64] = v[k];
        }
        #pragma unroll
        for (int e = 1; e <= kNE; ++e) {
            float p = 0.f;
            #pragma unroll
            for (int k = 0; k < 8; ++k) p += (av[k] == e) ? v[k] : 0.f;
            #pragma unroll
            for (int off = 32; off; off >>= 1) p += __shfl_xor(p, off);
            if (lane == 0) wsum[r][e] = p;
        }
    }
    __syncthreads();

    // Phase C: dense attn @ h, thread = (f4, rs row, jh j-half)
    const int f4 = (tid & 31) * 4;
    const int rs = (tid >> 5) & 7;
    const int jh = tid >> 8;
    const float* hb  = h + ((size_t)(b * kN + jh * 256)) * kFOUT + f4;
    const float* scr = &sc[rs][jh * 256];

    float4 acc = {0.f, 0.f, 0.f, 0.f};
    #pragma unroll 4
    for (int j = 0; j < 256; ++j) {
        const float  w  = scr[j];                              // LDS broadcast
        const float4 hv = *(const float4*)&hb[(size_t)j * kFOUT];
        acc.x = fmaf(w, hv.x, acc.x); acc.y = fmaf(w, hv.y, acc.y);
        acc.z = fmaf(w, hv.z, acc.z); acc.w = fmaf(w, hv.w, acc.w);
    }
    __syncthreads();                       // adjs dead; safe to reuse

    float* scratch = (float*)adjs;
    if (jh == 1)
        *(float4*)&scratch[(rs * 32 + (tid & 31)) * 4] = acc;
    __syncthreads();
    if (jh == 0) {
        const float4 o2 = *(const float4*)&scratch[(rs * 32 + (tid & 31)) * 4];
        acc.x += o2.x; acc.y += o2.y; acc.z += o2.z; acc.w += o2.w;
        #pragma unroll
        for (int e = 1; e <= kNE; ++e) {
            const float  wv = wsum[rs][e];
            const float4 ev = *(const float4*)&emb[e * kFOUT + f4];
            acc.x = fmaf(wv, ev.x, acc.x); acc.y = fmaf(wv, ev.y, acc.y);
            acc.z = fmaf(wv, ev.z, acc.z); acc.w = fmaf(wv, ev.w, acc.w);
        }
        acc.x = acc.x > 0.f ? acc.x : expm1f(acc.x);
        acc.y = acc.y > 0.f ? acc.y : expm1f(acc.y);
        acc.z = acc.z > 0.f ? acc.z : expm1f(acc.z);
        acc.w = acc.w > 0.f ? acc.w : expm1f(acc.w);
        *(float4*)&out[((size_t)(b * kN + i0 + rs)) * kFOUT + f4] = acc;
    }
}

// ---------------------------------------------------------------------------
extern "C" void kernel_launch(void* const* d_in, const int* in_sizes, int n_in,
                              void* d_out, int out_size, void* d_ws, size_t ws_size,
                              hipStream_t stream) {
    const float* node_rep = (const float*)d_in[0];
    const float* mask     = (const float*)d_in[1];
    const int*   adj      = (const int*)  d_in[2];
    const float* W        = (const float*)d_in[3];
    const float* bias     = (const float*)d_in[4];
    const float* a1       = (const float*)d_in[5];
    const float* a2       = (const float*)d_in[6];
    const float* a_b      = (const float*)d_in[7];
    const float* emb      = (const float*)d_in[8];
    float* out = (float*)d_out;

    float* ws     = (float*)d_ws;
    float* h      = ws;                            // B*N*FOUT (2 MB)
    float* s1     = h + (size_t)kBN * kFOUT;       // B*N
    float* s2     = s1 + kBN;                      // B*N
    float* emb_a2 = s2 + kBN;                      // 16

    proj_kernel<<<kBN / 8, 512, 0, stream>>>(
        node_rep, mask, W, bias, a1, a2, a_b, emb, h, s1, s2, emb_a2);
    attn_kernel<<<kBN / 8, 512, 0, stream>>>(
        adj, emb, h, s1, s2, emb_a2, out);
}

// Round 7
// 112.943 us; speedup vs baseline: 1.6215x; 1.1375x over previous
//
#include <hip/hip_runtime.h>

constexpr int kB    = 8;
constexpr int kN    = 512;
constexpr int kFIN  = 256;
constexpr int kFOUT = 128;
constexpr int kNE   = 10;
constexpr int kBN   = kB * kN;
constexpr float kALPHA = 0.2f;
constexpr float kNEG   = -9e15f;

// ---------------------------------------------------------------------------
// Kernel 1: typed projection + s1/s2 + emb.a2 table.
// Grid 512 x 256 threads, 8 rows/block. Thread = (o = tid&127, kq = tid>>7).
// Each thread: 8 rows x 1 out x 3 types over a 128-wide k-half (24 acc).
// W streamed from L2 with manual ping-pong prefetch (wA/wB). x broadcast from
// 8 KB LDS. 20 KB LDS.
// ---------------------------------------------------------------------------
__global__ __launch_bounds__(256) void proj_kernel(
    const float* __restrict__ node_rep,  // (B*N, FIN)
    const float* __restrict__ mask,      // (T, B*N)
    const float* __restrict__ W,         // (T, FIN, FOUT)
    const float* __restrict__ bias,      // (T, FOUT)
    const float* __restrict__ a1,
    const float* __restrict__ a2,
    const float* __restrict__ a_b,
    const float* __restrict__ emb,       // (NE+1, FOUT)
    float* __restrict__ h,               // (B*N, FOUT)
    float* __restrict__ s1,              // (B*N) a_b folded
    float* __restrict__ s2,              // (B*N)
    float* __restrict__ emb_a2)          // (16)
{
    __shared__ float xs[8][kFIN];          //  8 KB
    __shared__ float parts[3][8][kFOUT];   // 12 KB

    const int tid  = threadIdx.x;
    const int row0 = blockIdx.x * 8;
    const int o    = tid & 127;
    const int kq   = tid >> 7;             // 0..1 -> k in [kq*128, kq*128+128)

    #pragma unroll
    for (int it = 0; it < 2; ++it) {       // 512 quads total (8 rows x 64)
        const int idx = tid + it * 256;    // < 512
        const int r = idx >> 6, q = idx & 63;
        *(float4*)&xs[r][q * 4] =
            *(const float4*)&node_rep[(size_t)(row0 + r) * kFIN + q * 4];
    }
    __syncthreads();

    float acc[3][8];
    #pragma unroll
    for (int t = 0; t < 3; ++t)
        #pragma unroll
        for (int r = 0; r < 8; ++r) acc[t][r] = 0.f;

    const float* Wo = W + o;
    const int k0 = kq * 128;

    float wA[3][4], wB[3][4];
    auto loadw = [&](float (&buf)[3][4], int kk) {
        #pragma unroll
        for (int t = 0; t < 3; ++t)
            #pragma unroll
            for (int c = 0; c < 4; ++c)
                buf[t][c] = Wo[(t * kFIN + kk + c) * kFOUT];
    };
    auto fmab = [&](float (&buf)[3][4], int kb) {
        float4 xv[8];
        #pragma unroll
        for (int r = 0; r < 8; ++r)        // wave-uniform addr -> broadcast
            xv[r] = *(const float4*)&xs[r][kb];
        #pragma unroll
        for (int c = 0; c < 4; ++c)
            #pragma unroll
            for (int r = 0; r < 8; ++r) {
                const float x = ((const float*)&xv[r])[c];
                acc[0][r] = fmaf(buf[0][c], x, acc[0][r]);
                acc[1][r] = fmaf(buf[1][c], x, acc[1][r]);
                acc[2][r] = fmaf(buf[2][c], x, acc[2][r]);
            }
    };

    loadw(wA, k0);
    for (int i4 = 0; i4 < 32; i4 += 2) {
        loadw(wB, k0 + (i4 + 1) * 4);      // prefetch next chunk
        fmab(wA, k0 + i4 * 4);
        if (i4 + 2 < 32) loadw(wA, k0 + (i4 + 2) * 4);
        fmab(wB, k0 + (i4 + 1) * 4);
    }

    if (kq == 1) {
        #pragma unroll
        for (int t = 0; t < 3; ++t)
            #pragma unroll
            for (int r = 0; r < 8; ++r)
                parts[t][r][o] = acc[t][r];    // lanes stride-1: conflict-free
    }
    __syncthreads();

    if (kq == 0) {
        #pragma unroll
        for (int r = 0; r < 8; ++r) {
            const int row = row0 + r;
            float hv = 0.f;
            #pragma unroll
            for (int t = 0; t < 3; ++t) {
                const float s = acc[t][r] + parts[t][r][o] + bias[t * kFOUT + o];
                hv = fmaf(mask[t * kBN + row], s, hv);
            }
            h[(size_t)row * kFOUT + o] = hv;
            parts[0][r][o] = hv;           // stash for s1/s2 (own slot only)
        }
    }
    __syncthreads();

    // s1/s2: 4 waves x 2 rows
    {
        const int wv = tid >> 6, lane = tid & 63;
        #pragma unroll
        for (int rr = 0; rr < 2; ++rr) {
            const int r = wv * 2 + rr;
            const float v0 = parts[0][r][lane];
            const float v1 = parts[0][r][64 + lane];
            float p1 = v0 * a1[lane] + v1 * a1[64 + lane];
            float p2 = v0 * a2[lane] + v1 * a2[64 + lane];
            #pragma unroll
            for (int off = 32; off; off >>= 1) {
                p1 += __shfl_down(p1, off);
                p2 += __shfl_down(p2, off);
            }
            if (lane == 0) {
                s1[row0 + r] = p1 + a_b[0];
                s2[row0 + r] = p2;
            }
        }
    }

    // emb.a2 table once (block 0): 11 rows x 16 lanes
    if (blockIdx.x == 0 && tid < 176) {
        const int e = tid >> 4, l = tid & 15;
        float p = 0.f;
        #pragma unroll
        for (int k8 = 0; k8 < 8; ++k8)
            p += emb[e * kFOUT + l + k8 * 16] * a2[l + k8 * 16];
        #pragma unroll
        for (int off = 8; off; off >>= 1) p += __shfl_xor(p, off);
        if (l == 0) emb_a2[e] = p;
    }
}

// ---------------------------------------------------------------------------
// Kernel 2: scores + softmax + histogram + dense attn@h + ELU.
// Grid 512 x 256 threads, 8 i-rows/block.
// Phase C redundancy 2x: thread = (f4l:32, rg:2 row-groups, js:4 j-slices);
// h read 2x per block (512 KB L2 traffic vs 2 MB in round 4/5).
// scT[j][8] = transposed attn -> 1 b128 LDS broadcast per j in Phase C.
// j-partials combined via LDS (reuse dead adjs). ~49 KB LDS.
// ---------------------------------------------------------------------------
__global__ __launch_bounds__(256) void attn_kernel(
    const int*   __restrict__ adj,     // (B, N, N)
    const float* __restrict__ emb,     // (NE+1, FOUT)
    const float* __restrict__ h,       // (B*N, FOUT)
    const float* __restrict__ s1,      // (B*N) a_b folded
    const float* __restrict__ s2,      // (B*N)
    const float* __restrict__ emb_a2g, // (16)
    float* __restrict__ out)           // (B*N, FOUT)
{
    __shared__ float sc[8][kN + 4];    // 16.5 KB raw scores
    __shared__ int   adjs[8][kN];      // 16 KB (reused as float parts[4][8][128])
    __shared__ float scT[kN][8];       // 16 KB transposed attn
    __shared__ float wsum[8][16];
    __shared__ float ea2[16];

    const int tid = threadIdx.x;
    const int b   = blockIdx.x >> 6;
    const int i0  = (blockIdx.x & 63) * 8;

    if (tid < 16) ea2[tid] = emb_a2g[tid];
    __syncthreads();

    // Phase A: scores (int4/float4 global, float4/int4 LDS)
    const int*   adjb = adj + ((size_t)(b * kN + i0)) * kN;
    const float* s2b  = s2 + b * kN;
    #pragma unroll
    for (int it = 0; it < 4; ++it) {
        const int idx = tid + it * 256;      // quad index < 1024 (8 rows x 128)
        const int r = idx >> 7, jq = idx & 127;
        const int4   av  = *(const int4*)&adjb[(size_t)r * kN + jq * 4];
        const float4 s2v = *(const float4*)&s2b[jq * 4];
        const float  sr  = s1[b * kN + i0 + r];
        float4 sv; float s;
        s = sr + s2v.x + ea2[av.x]; s = s > 0.f ? s : kALPHA * s; sv.x = av.x > 0 ? s : kNEG;
        s = sr + s2v.y + ea2[av.y]; s = s > 0.f ? s : kALPHA * s; sv.y = av.y > 0 ? s : kNEG;
        s = sr + s2v.z + ea2[av.z]; s = s > 0.f ? s : kALPHA * s; sv.z = av.z > 0 ? s : kNEG;
        s = sr + s2v.w + ea2[av.w]; s = s > 0.f ? s : kALPHA * s; sv.w = av.w > 0 ? s : kNEG;
        *(float4*)&sc[r][jq * 4] = sv;
        *(int4*)&adjs[r][jq * 4] = av;
    }
    __syncthreads();

    // Phase B: softmax + histogram, 4 waves x 2 rows; writes transposed scT
    {
        const int wv = tid >> 6, lane = tid & 63;
        #pragma unroll
        for (int rr = 0; rr < 2; ++rr) {
            const int r = wv * 2 + rr;
            float v[8]; int av[8];
            #pragma unroll
            for (int k = 0; k < 8; ++k) {
                v[k]  = sc[r][lane + k * 64];
                av[k] = adjs[r][lane + k * 64];
            }
            float m = v[0];
            #pragma unroll
            for (int k = 1; k < 8; ++k) m = fmaxf(m, v[k]);
            #pragma unroll
            for (int off = 32; off; off >>= 1) m = fmaxf(m, __shfl_xor(m, off));
            float sum = 0.f;
            #pragma unroll
            for (int k = 0; k < 8; ++k) { v[k] = __expf(v[k] - m); sum += v[k]; }
            #pragma unroll
            for (int off = 32; off; off >>= 1) sum += __shfl_xor(sum, off);
            const float inv = 1.0f / sum;
            #pragma unroll
            for (int k = 0; k < 8; ++k) {
                v[k] *= inv;
                scT[lane + k * 64][r] = v[k];
            }
            #pragma unroll
            for (int e = 1; e <= kNE; ++e) {
                float p = 0.f;
                #pragma unroll
                for (int k = 0; k < 8; ++k) p += (av[k] == e) ? v[k] : 0.f;
                #pragma unroll
                for (int off = 32; off; off >>= 1) p += __shfl_xor(p, off);
                if (lane == 0) wsum[r][e] = p;
            }
        }
    }
    __syncthreads();

    // Phase C: dense attn @ h. thread = (f4l: 32 lanes, rg: 2, js: wave)
    const int f4l = tid & 31;
    const int rg  = (tid >> 5) & 1;
    const int js  = tid >> 6;              // 0..3, 128 j each
    const float* hb  = h + ((size_t)(b * kN + js * 128)) * kFOUT + f4l * 4;
    const float* sct = &scT[js * 128][rg * 4];

    float4 acc0 = {0,0,0,0}, acc1 = {0,0,0,0}, acc2 = {0,0,0,0}, acc3 = {0,0,0,0};
    #pragma unroll 4
    for (int jj = 0; jj < 128; ++jj) {
        const float4 w4 = *(const float4*)&sct[jj * 8];   // LDS b128 broadcast
        const float4 hv = *(const float4*)&hb[(size_t)jj * kFOUT];
        acc0.x = fmaf(w4.x, hv.x, acc0.x); acc0.y = fmaf(w4.x, hv.y, acc0.y);
        acc0.z = fmaf(w4.x, hv.z, acc0.z); acc0.w = fmaf(w4.x, hv.w, acc0.w);
        acc1.x = fmaf(w4.y, hv.x, acc1.x); acc1.y = fmaf(w4.y, hv.y, acc1.y);
        acc1.z = fmaf(w4.y, hv.z, acc1.z); acc1.w = fmaf(w4.y, hv.w, acc1.w);
        acc2.x = fmaf(w4.z, hv.x, acc2.x); acc2.y = fmaf(w4.z, hv.y, acc2.y);
        acc2.z = fmaf(w4.z, hv.z, acc2.z); acc2.w = fmaf(w4.z, hv.w, acc2.w);
        acc3.x = fmaf(w4.w, hv.x, acc3.x); acc3.y = fmaf(w4.w, hv.y, acc3.y);
        acc3.z = fmaf(w4.w, hv.z, acc3.z); acc3.w = fmaf(w4.w, hv.w, acc3.w);
    }
    __syncthreads();                       // adjs dead -> reuse as parts

    float* parts = (float*)adjs;           // [js 4][r 8][f 128]
    {
        const int rbase = rg * 4;
        *(float4*)&parts[((js * 8) + rbase + 0) * kFOUT + f4l * 4] = acc0;
        *(float4*)&parts[((js * 8) + rbase + 1) * kFOUT + f4l * 4] = acc1;
        *(float4*)&parts[((js * 8) + rbase + 2) * kFOUT + f4l * 4] = acc2;
        *(float4*)&parts[((js * 8) + rbase + 3) * kFOUT + f4l * 4] = acc3;
    }
    __syncthreads();

    // Reduction + emb correction + ELU + store: thread = (r = tid>>5, 4 f)
    {
        const int r  = tid >> 5;
        const int fl = (tid & 31) * 4;
        float4 a = {0,0,0,0};
        #pragma unroll
        for (int p = 0; p < 4; ++p) {
            const float4 pv = *(const float4*)&parts[((p * 8) + r) * kFOUT + fl];
            a.x += pv.x; a.y += pv.y; a.z += pv.z; a.w += pv.w;
        }
        #pragma unroll
        for (int e = 1; e <= kNE; ++e) {
            const float  wv = wsum[r][e];
            const float4 ev = *(const float4*)&emb[e * kFOUT + fl];
            a.x = fmaf(wv, ev.x, a.x); a.y = fmaf(wv, ev.y, a.y);
            a.z = fmaf(wv, ev.z, a.z); a.w = fmaf(wv, ev.w, a.w);
        }
        a.x = a.x > 0.f ? a.x : expm1f(a.x);
        a.y = a.y > 0.f ? a.y : expm1f(a.y);
        a.z = a.z > 0.f ? a.z : expm1f(a.z);
        a.w = a.w > 0.f ? a.w : expm1f(a.w);
        *(float4*)&out[((size_t)(b * kN + i0 + r)) * kFOUT + fl] = a;
    }
}

// ---------------------------------------------------------------------------
extern "C" void kernel_launch(void* const* d_in, const int* in_sizes, int n_in,
                              void* d_out, int out_size, void* d_ws, size_t ws_size,
                              hipStream_t stream) {
    const float* node_rep = (const float*)d_in[0];
    const float* mask     = (const float*)d_in[1];
    const int*   adj      = (const int*)  d_in[2];
    const float* W        = (const float*)d_in[3];
    const float* bias     = (const float*)d_in[4];
    const float* a1       = (const float*)d_in[5];
    const float* a2       = (const float*)d_in[6];
    const float* a_b      = (const float*)d_in[7];
    const float* emb      = (const float*)d_in[8];
    float* out = (float*)d_out;

    float* ws     = (float*)d_ws;
    float* h      = ws;                            // B*N*FOUT (2 MB)
    float* s1     = h + (size_t)kBN * kFOUT;       // B*N
    float* s2     = s1 + kBN;                      // B*N
    float* emb_a2 = s2 + kBN;                      // 16

    proj_kernel<<<kBN / 8, 256, 0, stream>>>(
        node_rep, mask, W, bias, a1, a2, a_b, emb, h, s1, s2, emb_a2);
    attn_kernel<<<kBN / 8, 256, 0, stream>>>(
        adj, emb, h, s1, s2, emb_a2, out);
}